// Round 2
// baseline (214.865 us; speedup 1.0000x reference)
//
#include <hip/hip_runtime.h>

#define DIM    256
#define HALF   128
#define F0     10
#define F1     25
#define B0     1024
#define M1     10240   // B0 * F0
#define NNODES 100000

typedef __attribute__((ext_vector_type(8))) short     bf16x8;  // 8 bf16 = 4 VGPRs
typedef __attribute__((ext_vector_type(4))) float     f32x4;

#define LSTRIDE 264   // LDS row stride in bf16 elems: 256 + 8 pad (528 B, 16B-aligned)

__device__ __forceinline__ unsigned short f2bf(float x) {
    union { float f; unsigned u; } v; v.f = x;
    unsigned r = v.u + 0x7fffu + ((v.u >> 16) & 1u);   // RNE
    return (unsigned short)(r >> 16);
}
__device__ __forceinline__ float bf2f(unsigned short b) {
    union { unsigned u; float f; } v; v.u = ((unsigned)b) << 16;
    return v.f;
}
// unpack a u32 holding 2 bf16 (lo = even elem, hi = odd elem) to 2 floats
__device__ __forceinline__ void up2(unsigned u, float& lo, float& hi) {
    union { unsigned x; float f; } a, b;
    a.x = u << 16; b.x = u & 0xffff0000u;
    lo = a.f; hi = b.f;
}
__device__ __forceinline__ void acc2(float& a, float& b, unsigned u) {
    float lo, hi; up2(u, lo, hi); a += lo; b += hi;
}
__device__ __forceinline__ unsigned pk(float lo, float hi) {
    return (unsigned)f2bf(lo) | ((unsigned)f2bf(hi) << 16);
}

// ---------- Prep: W0_{self,neigh} -> bf16 B-fragments in frag-linear order.
// B-frag for (mat, tile t, kstep kk), lane = q*16+n, j=0..7 : W[kk*32+q*8+j][t*16+n]
// stored at bfrag[((mat*64 + t*8+kk)*64 + lane)*8 + j].
__global__ __launch_bounds__(64) void prep_w(
    const float* __restrict__ Ws,
    const float* __restrict__ Wn,
    unsigned short* __restrict__ bfrag)
{
    const int bx   = blockIdx.x;       // [0,128)
    const int mat  = bx >> 6;
    const int f    = bx & 63;          // t*8+kk
    const int kk   = f & 7;
    const int t    = f >> 3;
    const int lane = threadIdx.x;
    const int n    = lane & 15, q = lane >> 4;
    const float* W = mat ? Wn : Ws;

    __align__(16) unsigned short tmp[8];
    #pragma unroll
    for (int j = 0; j < 8; ++j)
        tmp[j] = f2bf(W[(kk * 32 + q * 8 + j) * HALF + t * 16 + n]);
    *(uint4*)(bfrag + ((size_t)(mat * 64 + f) * 64 + lane) * 8) = *(const uint4*)tmp;
}

// ---------- Precompute G = bf16(feat) @ [W0_self | W0_neigh], stored bf16 [node][256].
// Mean commutes with the linear map, so layer-0 becomes gather+mean+ReLU over G
// (256 B bf16 half-rows instead of 1 KB fp32 feature rows => 4x less random traffic).
// Block: 512 threads / 8 waves, 32 feature rows. 100000 = 3125 * 32 exactly.
__global__ __launch_bounds__(512, 4) void precompute_g(
    const float* __restrict__ feat,
    const unsigned short* __restrict__ bfrag,
    unsigned short* __restrict__ G)
{
    __shared__ __align__(16) unsigned short sh[2][16][LSTRIDE];  // 32 rows of bf16 features

    const int tid  = threadIdx.x;
    const int wv   = __builtin_amdgcn_readfirstlane(tid >> 6);   // 0..7
    const int lane = tid & 63;
    const int base = blockIdx.x * 32;

    // stage: each wave converts 4 rows (lane covers 4 consecutive floats)
    #pragma unroll
    for (int rr = 0; rr < 4; ++rr) {
        const int r = wv * 4 + rr;                               // 0..31
        const float4 sv = *(const float4*)(feat + (size_t)(base + r) * DIM + lane * 4);
        unsigned short s4[4] = { f2bf(sv.x), f2bf(sv.y), f2bf(sv.z), f2bf(sv.w) };
        *(uint2*)(&sh[r >> 4][r & 15][lane * 4]) = *(const uint2*)s4;
    }
    __syncthreads();

    // MFMA: wave wv -> row-group h = wv>>2 (16 rows), tile-pair tp = wv&3.
    // Per mat (self|neigh): tiles {2tp, 2tp+1}; 4 accumulators cover both mats.
    const int h  = wv >> 2;
    const int tp = wv & 3;
    const int m  = lane & 15;
    const int q  = lane >> 4;

    f32x4 acc[4] = { {0.f,0.f,0.f,0.f}, {0.f,0.f,0.f,0.f},
                     {0.f,0.f,0.f,0.f}, {0.f,0.f,0.f,0.f} };

    #pragma unroll
    for (int kk = 0; kk < 8; ++kk) {
        const bf16x8 af = *(const bf16x8*)(&sh[h][m][kk * 32 + q * 8]);
        #pragma unroll
        for (int i = 0; i < 4; ++i) {
            const int mat = i >> 1;
            const int t   = tp * 2 + (i & 1);
            const bf16x8 bf = *(const bf16x8*)(bfrag + ((size_t)(mat * 64 + t * 8 + kk) * 64 + lane) * 8);
            acc[i] = __builtin_amdgcn_mfma_f32_16x16x32_bf16(af, bf, acc[i], 0, 0, 0);
        }
    }

    // epilogue: C/D layout col = lane&15, row = q*4 + reg. NO relu here (relu is
    // applied after the mean in the gather kernel).
    #pragma unroll
    for (int i = 0; i < 4; ++i) {
        const int mat = i >> 1;
        const int t   = tp * 2 + (i & 1);
        const int col = mat * HALF + t * 16 + m;
        #pragma unroll
        for (int reg = 0; reg < 4; ++reg) {
            const int row = base + h * 16 + q * 4 + reg;
            G[(size_t)row * DIM + col] = f2bf(acc[i][reg]);
        }
    }
}

// ---------- Layer-0 via G: per row r, out = [relu(Gs[self[r]]), relu(mean_j Gn[nb[r,j]])].
// 16 lanes per row, each lane owns 8 consecutive cols (16 B bf16 load per row read).
template<int NF, bool FP32OUT>
__device__ __forceinline__ void gather_hop(
    const unsigned short* __restrict__ G,
    const int* __restrict__ selfIdx,
    const int* __restrict__ neighIdx,
    int rowbase,
    int* s_self, int* s_nb,
    float*          __restrict__ dstF,   // hop0: n0 fp32 (in d_out)
    unsigned short* __restrict__ dstB)   // hop1: n1 bf16 (in ws)
{
    const int tid = threadIdx.x;   // 256

    // stage the block's indices into LDS (decouples idx->data dependent chain)
    for (int t = tid; t < 16 * NF; t += 256) s_nb[t] = neighIdx[rowbase * NF + t];
    if (tid < 16) s_self[tid] = selfIdx[rowbase + tid];
    __syncthreads();

    const int slot = tid >> 4;     // 0..15  (row within block)
    const int sub  = tid & 15;     // 16 B chunk within 256 B half-row
    const int row  = rowbase + slot;

    // ---- self half: cols [0,128)
    {
        const int si = s_self[slot];
        const uint4 v = *(const uint4*)(G + (size_t)si * DIM + sub * 8);
        float f[8];
        up2(v.x, f[0], f[1]); up2(v.y, f[2], f[3]);
        up2(v.z, f[4], f[5]); up2(v.w, f[6], f[7]);
        if (FP32OUT) {
            float4 o0 = { fmaxf(f[0],0.f), fmaxf(f[1],0.f), fmaxf(f[2],0.f), fmaxf(f[3],0.f) };
            float4 o1 = { fmaxf(f[4],0.f), fmaxf(f[5],0.f), fmaxf(f[6],0.f), fmaxf(f[7],0.f) };
            *(float4*)(dstF + (size_t)row * DIM + sub * 8)     = o0;
            *(float4*)(dstF + (size_t)row * DIM + sub * 8 + 4) = o1;
        } else {
            uint4 o;
            o.x = pk(fmaxf(f[0],0.f), fmaxf(f[1],0.f));
            o.y = pk(fmaxf(f[2],0.f), fmaxf(f[3],0.f));
            o.z = pk(fmaxf(f[4],0.f), fmaxf(f[5],0.f));
            o.w = pk(fmaxf(f[6],0.f), fmaxf(f[7],0.f));
            *(uint4*)(dstB + (size_t)row * DIM + sub * 8) = o;
        }
    }

    // ---- neighbor half: cols [128,256): mean over NF gathered Gn half-rows
    {
        float a[8] = {0.f,0.f,0.f,0.f,0.f,0.f,0.f,0.f};
        #pragma unroll 5
        for (int j = 0; j < NF; ++j) {
            const int gi = s_nb[slot * NF + j];
            const uint4 v = *(const uint4*)(G + (size_t)gi * DIM + HALF + sub * 8);
            acc2(a[0], a[1], v.x); acc2(a[2], a[3], v.y);
            acc2(a[4], a[5], v.z); acc2(a[6], a[7], v.w);
        }
        const float sc = 1.0f / (float)NF;
        #pragma unroll
        for (int k = 0; k < 8; ++k) a[k] = fmaxf(a[k] * sc, 0.f);
        if (FP32OUT) {
            float4 o0 = { a[0], a[1], a[2], a[3] };
            float4 o1 = { a[4], a[5], a[6], a[7] };
            *(float4*)(dstF + (size_t)row * DIM + HALF + sub * 8)     = o0;
            *(float4*)(dstF + (size_t)row * DIM + HALF + sub * 8 + 4) = o1;
        } else {
            uint4 o;
            o.x = pk(a[0], a[1]); o.y = pk(a[2], a[3]);
            o.z = pk(a[4], a[5]); o.w = pk(a[6], a[7]);
            *(uint4*)(dstB + (size_t)row * DIM + HALF + sub * 8) = o;
        }
    }
}

__global__ __launch_bounds__(256) void sage_gather(
    const unsigned short* __restrict__ G,
    const int* __restrict__ sn0,
    const int* __restrict__ sn1,
    const int* __restrict__ sn2,
    float*          __restrict__ n0,
    unsigned short* __restrict__ n1)
{
    __shared__ int s_self[16];
    __shared__ int s_nb[16 * F1];

    int gb = blockIdx.x;
    if (gb < B0 / 16) {
        gather_hop<F0, true >(G, sn0, sn1, gb * 16, s_self, s_nb, n0, nullptr);
    } else {
        gb -= B0 / 16;
        gather_hop<F1, false>(G, sn1, sn2, gb * 16, s_self, s_nb, nullptr, n1);
    }
}

// ---------- Final layer: out = concat(n0 @ W1s, mean10(n1) @ W1n), fp32 VALU.
#define PAD 260
#define R2  4

__global__ __launch_bounds__(256) void sage_final(
    const unsigned short* __restrict__ n1,
    const float* __restrict__ W1s,
    const float* __restrict__ W1n,
    float*       out)              // aliases n0 input — no restrict
{
    __shared__ float sh_n0 [R2][PAD];
    __shared__ float sh_agg[R2][PAD];

    const int tid     = threadIdx.x;
    const int rowbase = blockIdx.x * R2;
    const int wave    = tid >> 6;
    const int lane    = tid & 63;

    {
        const int r = wave;
        *(float4*)(&sh_n0[r][lane * 4]) =
            *(const float4*)(out + (size_t)(rowbase + r) * DIM + lane * 4);

        const unsigned short* base = n1 + ((size_t)(rowbase + r) * F0) * DIM + lane * 4;
        float4 a = make_float4(0.f, 0.f, 0.f, 0.f);
        #pragma unroll
        for (int j = 0; j < F0; ++j) {
            const uint2 p = *(const uint2*)(base + (size_t)j * DIM);
            a.x += bf2f((unsigned short)(p.x & 0xffff));
            a.y += bf2f((unsigned short)(p.x >> 16));
            a.z += bf2f((unsigned short)(p.y & 0xffff));
            a.w += bf2f((unsigned short)(p.y >> 16));
        }
        const float sc = 1.0f / (float)F0;
        a.x *= sc; a.y *= sc; a.z *= sc; a.w *= sc;
        *(float4*)(&sh_agg[r][lane * 4]) = a;
    }
    __syncthreads();

    const int  u     = tid & 127;
    const int  c0    = u * 2;
    const int  rb    = (tid >> 7) * 2;
    const bool neigh = (c0 >= HALF);
    const float* __restrict__ W = neigh ? W1n : W1s;
    const int  col   = neigh ? (c0 - HALF) : c0;
    const float (*src)[PAD] = neigh ? sh_agg : sh_n0;

    float a0[2] = {0.f, 0.f}, a1[2] = {0.f, 0.f};
    for (int d = 0; d < DIM; d += 4) {
        const float2 w0 = *(const float2*)(W + (d + 0) * HALF + col);
        const float2 w1 = *(const float2*)(W + (d + 1) * HALF + col);
        const float2 w2 = *(const float2*)(W + (d + 2) * HALF + col);
        const float2 w3 = *(const float2*)(W + (d + 3) * HALF + col);
        #pragma unroll
        for (int r = 0; r < 2; ++r) {
            const float4 hh = *(const float4*)(&src[rb + r][d]);
            a0[r] += hh.x * w0.x + hh.y * w1.x + hh.z * w2.x + hh.w * w3.x;
            a1[r] += hh.x * w0.y + hh.y * w1.y + hh.z * w2.y + hh.w * w3.y;
        }
    }

    #pragma unroll
    for (int r = 0; r < 2; ++r) {
        float2 o;
        o.x = a0[r];
        o.y = a1[r];
        *(float2*)(out + (size_t)(rowbase + rb + r) * DIM + c0) = o;
    }
}

extern "C" void kernel_launch(void* const* d_in, const int* in_sizes, int n_in,
                              void* d_out, int out_size, void* d_ws, size_t ws_size,
                              hipStream_t stream) {
    (void)in_sizes; (void)n_in; (void)out_size; (void)ws_size;
    const float* feat = (const float*)d_in[0];
    const int*   sn0  = (const int*)  d_in[1];
    const int*   sn1  = (const int*)  d_in[2];
    const int*   sn2  = (const int*)  d_in[3];
    const float* W0s  = (const float*)d_in[4];
    const float* W0n  = (const float*)d_in[5];
    const float* W1s  = (const float*)d_in[6];
    const float* W1n  = (const float*)d_in[7];
    float* out = (float*)d_out;

    // ws layout (total ~56.6 MB; harness ws is ~400 MB per round-0 poison fill):
    //   [0, 5,242,880)               n1 bf16  (10240 x 256 x 2)
    //   [5,242,880, 5,373,952)       W0 B-fragments (128 KB, 16B-aligned)
    //   [5,373,952, +51,200,000)     G bf16   (100000 x 256 x 2)
    unsigned short* n1    = (unsigned short*)d_ws;
    unsigned short* bfrag = (unsigned short*)((char*)d_ws + (size_t)M1 * DIM * 2);
    unsigned short* G     = (unsigned short*)((char*)d_ws + (size_t)M1 * DIM * 2 + 131072);

    prep_w<<<128, 64, 0, stream>>>(W0s, W0n, bfrag);
    precompute_g<<<NNODES / 32, 512, 0, stream>>>(feat, bfrag, G);
    // n0 (1024x256 fp32) staged in d_out, then overwritten in-place by sage_final.
    sage_gather<<<(B0 + M1) / 16, 256, 0, stream>>>(G, sn0, sn1, sn2, out, n1);
    sage_final<<<B0 / R2, 256, 0, stream>>>(n1, W1s, W1n, out);
}

// Round 3
// 196.384 us; speedup vs baseline: 1.0941x; 1.0941x over previous
//
#include <hip/hip_runtime.h>

#define DIM    256
#define HALF   128
#define F0     10
#define F1     25
#define B0     1024
#define M1     10240   // B0 * F0
#define NNODES 100000
#define NGRP   3125    // NNODES / 32

typedef __attribute__((ext_vector_type(8))) short     bf16x8;  // 8 bf16 = 4 VGPRs
typedef __attribute__((ext_vector_type(4))) float     f32x4;

#define LSTRIDE 264   // LDS row stride in bf16 elems: 256 + 8 pad (528 B, 16B-aligned)

__device__ __forceinline__ unsigned short f2bf(float x) {
    union { float f; unsigned u; } v; v.f = x;
    unsigned r = v.u + 0x7fffu + ((v.u >> 16) & 1u);   // RNE
    return (unsigned short)(r >> 16);
}
__device__ __forceinline__ float bf2f(unsigned short b) {
    union { unsigned u; float f; } v; v.u = ((unsigned)b) << 16;
    return v.f;
}
// unpack a u32 holding 2 bf16 (lo = even elem, hi = odd elem) to 2 floats
__device__ __forceinline__ void up2(unsigned u, float& lo, float& hi) {
    union { unsigned x; float f; } a, b;
    a.x = u << 16; b.x = u & 0xffff0000u;
    lo = a.f; hi = b.f;
}
__device__ __forceinline__ void acc2(float& a, float& b, unsigned u) {
    float lo, hi; up2(u, lo, hi); a += lo; b += hi;
}
__device__ __forceinline__ unsigned pk(float lo, float hi) {
    return (unsigned)f2bf(lo) | ((unsigned)f2bf(hi) << 16);
}

// ---------- Prep: W0_{self,neigh} -> bf16 B-fragments in frag-linear order.
// B-frag for (mat, tile t, kstep kk), lane = q*16+n, j=0..7 : W[kk*32+q*8+j][t*16+n]
// stored at bfrag[((mat*64 + t*8+kk)*64 + lane)*8 + j].
__global__ __launch_bounds__(64) void prep_w(
    const float* __restrict__ Ws,
    const float* __restrict__ Wn,
    unsigned short* __restrict__ bfrag)
{
    const int bx   = blockIdx.x;       // [0,128)
    const int mat  = bx >> 6;
    const int f    = bx & 63;          // t*8+kk
    const int kk   = f & 7;
    const int t    = f >> 3;
    const int lane = threadIdx.x;
    const int n    = lane & 15, q = lane >> 4;
    const float* W = mat ? Wn : Ws;

    __align__(16) unsigned short tmp[8];
    #pragma unroll
    for (int j = 0; j < 8; ++j)
        tmp[j] = f2bf(W[(kk * 32 + q * 8 + j) * HALF + t * 16 + n]);
    *(uint4*)(bfrag + ((size_t)(mat * 64 + f) * 64 + lane) * 8) = *(const uint4*)tmp;
}

// ---------- Precompute G = bf16(feat) @ [W0_self | W0_neigh], stored bf16 [node][256].
// Persistent: 256 blocks (1/CU), whole bfrag (128 KB) staged in LDS ONCE per block
// (kills the ~800 MB of per-block L2 bfrag re-reads that made v1 latency-bound).
// Per iteration: 32 feature rows staged to LDS (bf16), next iteration's rows
// prefetched into registers so HBM latency hides under the MFMA phase.
__global__ __launch_bounds__(512) void precompute_g(
    const float* __restrict__ feat,
    const unsigned short* __restrict__ bfrag,
    unsigned short* __restrict__ G)
{
    __shared__ __align__(16) unsigned short bsh[2 * 64 * 64 * 8];   // 128 KB: all B-fragments
    __shared__ __align__(16) unsigned short ash[2][16][LSTRIDE];    // 16.9 KB: 32 A rows

    const int tid  = threadIdx.x;
    const int wv   = __builtin_amdgcn_readfirstlane(tid >> 6);   // 0..7
    const int lane = tid & 63;
    const int h    = wv >> 2;          // row-group (0..1)
    const int tp   = wv & 3;           // tile-pair
    const int m    = lane & 15;
    const int q    = lane >> 4;

    // one-time: stage all W0 B-fragments into LDS (131072 B = 8192 uint4, coalesced)
    {
        const uint4* src = (const uint4*)bfrag;
        uint4*       dst = (uint4*)bsh;
        #pragma unroll
        for (int i = 0; i < 16; ++i)
            dst[tid + i * 512] = src[tid + i * 512];
    }
    // first barrier inside the loop also fences these writes before any bsh read.

    int g = blockIdx.x;
    float4 pre[4];
    if (g < NGRP) {
        #pragma unroll
        for (int rr = 0; rr < 4; ++rr)
            pre[rr] = *(const float4*)(feat + (size_t)(g * 32 + wv * 4 + rr) * DIM + lane * 4);
    }

    for (; g < NGRP; g += 256) {
        // convert + write this iteration's 32 A rows (wave wv owns rows wv*4..wv*4+3)
        #pragma unroll
        for (int rr = 0; rr < 4; ++rr) {
            const int r = wv * 4 + rr;
            unsigned short s4[4] = { f2bf(pre[rr].x), f2bf(pre[rr].y),
                                     f2bf(pre[rr].z), f2bf(pre[rr].w) };
            *(uint2*)(&ash[r >> 4][r & 15][lane * 4]) = *(const uint2*)s4;
        }
        __syncthreads();

        // prefetch next row-group into registers (latency hides under MFMA phase)
        const int gn = g + 256;
        float4 nxt[4];
        if (gn < NGRP) {
            #pragma unroll
            for (int rr = 0; rr < 4; ++rr)
                nxt[rr] = *(const float4*)(feat + (size_t)(gn * 32 + wv * 4 + rr) * DIM + lane * 4);
        }

        f32x4 acc[4] = { {0.f,0.f,0.f,0.f}, {0.f,0.f,0.f,0.f},
                         {0.f,0.f,0.f,0.f}, {0.f,0.f,0.f,0.f} };

        #pragma unroll
        for (int kk = 0; kk < 8; ++kk) {
            const bf16x8 af = *(const bf16x8*)(&ash[h][m][kk * 32 + q * 8]);
            #pragma unroll
            for (int i = 0; i < 4; ++i) {
                const int mat = i >> 1;
                const int t   = tp * 2 + (i & 1);
                const bf16x8 bf = *(const bf16x8*)(&bsh[((mat * 64 + t * 8 + kk) * 64 + lane) * 8]);
                acc[i] = __builtin_amdgcn_mfma_f32_16x16x32_bf16(af, bf, acc[i], 0, 0, 0);
            }
        }

        // epilogue: C/D layout col = lane&15, row = q*4 + reg. No relu (applied post-mean).
        const int base = g * 32;
        #pragma unroll
        for (int i = 0; i < 4; ++i) {
            const int mat = i >> 1;
            const int t   = tp * 2 + (i & 1);
            const int col = mat * HALF + t * 16 + m;
            #pragma unroll
            for (int reg = 0; reg < 4; ++reg) {
                const int row = base + h * 16 + q * 4 + reg;
                G[(size_t)row * DIM + col] = f2bf(acc[i][reg]);
            }
        }
        __syncthreads();   // A-LDS reads done before next iteration overwrites

        #pragma unroll
        for (int rr = 0; rr < 4; ++rr) pre[rr] = nxt[rr];
    }
}

// ---------- Layer-0 via G: per row r, out = [relu(Gs[self[r]]), relu(mean_j Gn[nb[r,j]])].
// 16 lanes per row, each lane owns 8 consecutive cols (16 B bf16 load per row read).
template<int NF, bool FP32OUT>
__device__ __forceinline__ void gather_hop(
    const unsigned short* __restrict__ G,
    const int* __restrict__ selfIdx,
    const int* __restrict__ neighIdx,
    int rowbase,
    int* s_self, int* s_nb,
    float*          __restrict__ dstF,   // hop0: n0 fp32 (in d_out)
    unsigned short* __restrict__ dstB)   // hop1: n1 bf16 (in ws)
{
    const int tid = threadIdx.x;   // 256

    // stage the block's indices into LDS (decouples idx->data dependent chain)
    for (int t = tid; t < 16 * NF; t += 256) s_nb[t] = neighIdx[rowbase * NF + t];
    if (tid < 16) s_self[tid] = selfIdx[rowbase + tid];
    __syncthreads();

    const int slot = tid >> 4;     // 0..15  (row within block)
    const int sub  = tid & 15;     // 16 B chunk within 256 B half-row
    const int row  = rowbase + slot;

    // ---- self half: cols [0,128)
    {
        const int si = s_self[slot];
        const uint4 v = *(const uint4*)(G + (size_t)si * DIM + sub * 8);
        float f[8];
        up2(v.x, f[0], f[1]); up2(v.y, f[2], f[3]);
        up2(v.z, f[4], f[5]); up2(v.w, f[6], f[7]);
        if (FP32OUT) {
            float4 o0 = { fmaxf(f[0],0.f), fmaxf(f[1],0.f), fmaxf(f[2],0.f), fmaxf(f[3],0.f) };
            float4 o1 = { fmaxf(f[4],0.f), fmaxf(f[5],0.f), fmaxf(f[6],0.f), fmaxf(f[7],0.f) };
            *(float4*)(dstF + (size_t)row * DIM + sub * 8)     = o0;
            *(float4*)(dstF + (size_t)row * DIM + sub * 8 + 4) = o1;
        } else {
            uint4 o;
            o.x = pk(fmaxf(f[0],0.f), fmaxf(f[1],0.f));
            o.y = pk(fmaxf(f[2],0.f), fmaxf(f[3],0.f));
            o.z = pk(fmaxf(f[4],0.f), fmaxf(f[5],0.f));
            o.w = pk(fmaxf(f[6],0.f), fmaxf(f[7],0.f));
            *(uint4*)(dstB + (size_t)row * DIM + sub * 8) = o;
        }
    }

    // ---- neighbor half: cols [128,256): mean over NF gathered Gn half-rows
    {
        float a[8] = {0.f,0.f,0.f,0.f,0.f,0.f,0.f,0.f};
        #pragma unroll 5
        for (int j = 0; j < NF; ++j) {
            const int gi = s_nb[slot * NF + j];
            const uint4 v = *(const uint4*)(G + (size_t)gi * DIM + HALF + sub * 8);
            acc2(a[0], a[1], v.x); acc2(a[2], a[3], v.y);
            acc2(a[4], a[5], v.z); acc2(a[6], a[7], v.w);
        }
        const float sc = 1.0f / (float)NF;
        #pragma unroll
        for (int k = 0; k < 8; ++k) a[k] = fmaxf(a[k] * sc, 0.f);
        if (FP32OUT) {
            float4 o0 = { a[0], a[1], a[2], a[3] };
            float4 o1 = { a[4], a[5], a[6], a[7] };
            *(float4*)(dstF + (size_t)row * DIM + HALF + sub * 8)     = o0;
            *(float4*)(dstF + (size_t)row * DIM + HALF + sub * 8 + 4) = o1;
        } else {
            uint4 o;
            o.x = pk(a[0], a[1]); o.y = pk(a[2], a[3]);
            o.z = pk(a[4], a[5]); o.w = pk(a[6], a[7]);
            *(uint4*)(dstB + (size_t)row * DIM + HALF + sub * 8) = o;
        }
    }
}

__global__ __launch_bounds__(256) void sage_gather(
    const unsigned short* __restrict__ G,
    const int* __restrict__ sn0,
    const int* __restrict__ sn1,
    const int* __restrict__ sn2,
    float*          __restrict__ n0,
    unsigned short* __restrict__ n1)
{
    __shared__ int s_self[16];
    __shared__ int s_nb[16 * F1];

    int gb = blockIdx.x;
    if (gb < B0 / 16) {
        gather_hop<F0, true >(G, sn0, sn1, gb * 16, s_self, s_nb, n0, nullptr);
    } else {
        gb -= B0 / 16;
        gather_hop<F1, false>(G, sn1, sn2, gb * 16, s_self, s_nb, nullptr, n1);
    }
}

// ---------- Final layer: out = concat(n0 @ W1s, mean10(n1) @ W1n), fp32 VALU.
#define PAD 260
#define R2  4

__global__ __launch_bounds__(256) void sage_final(
    const unsigned short* __restrict__ n1,
    const float* __restrict__ W1s,
    const float* __restrict__ W1n,
    float*       out)              // aliases n0 input — no restrict
{
    __shared__ float sh_n0 [R2][PAD];
    __shared__ float sh_agg[R2][PAD];

    const int tid     = threadIdx.x;
    const int rowbase = blockIdx.x * R2;
    const int wave    = tid >> 6;
    const int lane    = tid & 63;

    {
        const int r = wave;
        *(float4*)(&sh_n0[r][lane * 4]) =
            *(const float4*)(out + (size_t)(rowbase + r) * DIM + lane * 4);

        const unsigned short* base = n1 + ((size_t)(rowbase + r) * F0) * DIM + lane * 4;
        float4 a = make_float4(0.f, 0.f, 0.f, 0.f);
        #pragma unroll
        for (int j = 0; j < F0; ++j) {
            const uint2 p = *(const uint2*)(base + (size_t)j * DIM);
            a.x += bf2f((unsigned short)(p.x & 0xffff));
            a.y += bf2f((unsigned short)(p.x >> 16));
            a.z += bf2f((unsigned short)(p.y & 0xffff));
            a.w += bf2f((unsigned short)(p.y >> 16));
        }
        const float sc = 1.0f / (float)F0;
        a.x *= sc; a.y *= sc; a.z *= sc; a.w *= sc;
        *(float4*)(&sh_agg[r][lane * 4]) = a;
    }
    __syncthreads();

    const int  u     = tid & 127;
    const int  c0    = u * 2;
    const int  rb    = (tid >> 7) * 2;
    const bool neigh = (c0 >= HALF);
    const float* __restrict__ W = neigh ? W1n : W1s;
    const int  col   = neigh ? (c0 - HALF) : c0;
    const float (*src)[PAD] = neigh ? sh_agg : sh_n0;

    float a0[2] = {0.f, 0.f}, a1[2] = {0.f, 0.f};
    for (int d = 0; d < DIM; d += 4) {
        const float2 w0 = *(const float2*)(W + (d + 0) * HALF + col);
        const float2 w1 = *(const float2*)(W + (d + 1) * HALF + col);
        const float2 w2 = *(const float2*)(W + (d + 2) * HALF + col);
        const float2 w3 = *(const float2*)(W + (d + 3) * HALF + col);
        #pragma unroll
        for (int r = 0; r < 2; ++r) {
            const float4 hh = *(const float4*)(&src[rb + r][d]);
            a0[r] += hh.x * w0.x + hh.y * w1.x + hh.z * w2.x + hh.w * w3.x;
            a1[r] += hh.x * w0.y + hh.y * w1.y + hh.z * w2.y + hh.w * w3.y;
        }
    }

    #pragma unroll
    for (int r = 0; r < 2; ++r) {
        float2 o;
        o.x = a0[r];
        o.y = a1[r];
        *(float2*)(out + (size_t)(rowbase + rb + r) * DIM + c0) = o;
    }
}

extern "C" void kernel_launch(void* const* d_in, const int* in_sizes, int n_in,
                              void* d_out, int out_size, void* d_ws, size_t ws_size,
                              hipStream_t stream) {
    (void)in_sizes; (void)n_in; (void)out_size; (void)ws_size;
    const float* feat = (const float*)d_in[0];
    const int*   sn0  = (const int*)  d_in[1];
    const int*   sn1  = (const int*)  d_in[2];
    const int*   sn2  = (const int*)  d_in[3];
    const float* W0s  = (const float*)d_in[4];
    const float* W0n  = (const float*)d_in[5];
    const float* W1s  = (const float*)d_in[6];
    const float* W1n  = (const float*)d_in[7];
    float* out = (float*)d_out;

    // ws layout (total ~56.6 MB):
    //   [0, 5,242,880)               n1 bf16  (10240 x 256 x 2)
    //   [5,242,880, 5,373,952)       W0 B-fragments (128 KB, 16B-aligned)
    //   [5,373,952, +51,200,000)     G bf16   (100000 x 256 x 2)
    unsigned short* n1    = (unsigned short*)d_ws;
    unsigned short* bfrag = (unsigned short*)((char*)d_ws + (size_t)M1 * DIM * 2);
    unsigned short* G     = (unsigned short*)((char*)d_ws + (size_t)M1 * DIM * 2 + 131072);

    prep_w<<<128, 64, 0, stream>>>(W0s, W0n, bfrag);
    precompute_g<<<256, 512, 0, stream>>>(feat, bfrag, G);
    // n0 (1024x256 fp32) staged in d_out, then overwritten in-place by sage_final.
    sage_gather<<<(B0 + M1) / 16, 256, 0, stream>>>(G, sn0, sn1, sn2, out, n1);
    sage_final<<<B0 / R2, 256, 0, stream>>>(n1, W1s, W1n, out);
}